// Round 1
// baseline (160.195 us; speedup 1.0000x reference)
//
#include <hip/hip_runtime.h>
#include <math.h>

#define B   64
#define NV  40000
#define P   100
#define KG  128
#define NJ  24
#define TVJ 16          // vertices per jpart sub-tile
#define TVS 32          // vertices per skin block (was 16)
#define NSK 31          // skeleton joints: 1 zero + 23 + 7
#define NSUB (KG / TVJ) // 8 sub-tiles per joint

typedef __attribute__((ext_vector_type(8))) short bf16x8;
typedef __attribute__((ext_vector_type(4))) float f32x4;

__device__ __forceinline__ unsigned short rne_bf16(float f) {
  unsigned u = __float_as_uint(f);
  u = (u + 0x7FFFu + ((u >> 16) & 1u)) >> 16;
  return (unsigned short)u;
}

// ---------------------------------------------------------------------------
// Kernel 1: partial joint keypoints — bf16 MFMA. Now 512 threads/block:
// the scattered sd gather is latency-bound at 184 blocks (<1 block/CU);
// 8 waves/block doubles waves/SIMD for latency hiding. GEMM stays on
// waves 0-3 (it is ~1us of the kernel); all barriers are block-uniform.
// ---------------------------------------------------------------------------
__global__ __launch_bounds__(512)
void k_jpart(const float* __restrict__ beta,
             const float* __restrict__ sd,
             const float* __restrict__ vt,
             const int*   __restrict__ joint_idx,
             float*       __restrict__ pmn,
             float*       __restrict__ pmx) {
  const int j = blockIdx.x;   // 0..22
  const int s = blockIdx.y;   // 0..7
  const int t = threadIdx.x;  // 0..511
  const int lane = t & 63, wv = t >> 6;
  const int l15 = lane & 15, qd = lane >> 4;

  __shared__ __align__(16) unsigned short beta_s[64 * 136];  // A: 17408 B
  __shared__ __align__(16) unsigned short sdT_s[48 * 136];   // B: 13056 B
  __shared__ float vt_s[48];
  __shared__ int   idx_s[TVJ];
  float* pos_s = (float*)beta_s;   // alias after phase 1: [b][68] f (exact)

  if (t < TVJ) idx_s[t] = joint_idx[j * KG + s * TVJ + t];
  __syncthreads();

  // beta -> bf16 LDS rows [m][136] (k padding zeroed; disjoint regions)
  for (int e = t; e < 64 * 36; e += 512) {
    const int m = e / 36, pp = P + e % 36;
    beta_s[m * 136 + pp] = 0;
  }
  for (int e = t; e < 64 * P; e += 512) {
    const int m = e / P, p = e % P;
    beta_s[m * 136 + p] = rne_bf16(beta[e]);
  }
  // sdT gather: tasks (n 0..47, kg 0..15), 8 rows each, scattered columns
  for (int task = t; task < 768; task += 512) {
    const int n = task % 48, kg = task / 48;
    const size_t colbase = (size_t)idx_s[n / 3] * 3 + (n % 3);
    unsigned pk[4];
#pragma unroll
    for (int h = 0; h < 4; ++h) {
      const int k0 = kg * 8 + 2 * h;
      float f0 = 0.0f, f1 = 0.0f;
      if (k0 < P)     f0 = sd[(size_t)k0 * (3 * NV) + colbase];
      if (k0 + 1 < P) f1 = sd[(size_t)(k0 + 1) * (3 * NV) + colbase];
      pk[h] = (unsigned)rne_bf16(f0) | ((unsigned)rne_bf16(f1) << 16);
    }
    *(uint4*)&sdT_s[n * 136 + kg * 8] = make_uint4(pk[0], pk[1], pk[2], pk[3]);
  }
  if (t < 48) vt_s[t] = vt[(size_t)idx_s[t / 3] * 3 + (t % 3)];
  __syncthreads();

  // phase 1: D(64x48) = beta(64x128) @ sdT(128x48), waves 0..3 only
  f32x4 acc[3];
  float vtv[3];
  if (wv < 4) {
    bf16x8 af[4];
#pragma unroll
    for (int ks = 0; ks < 4; ++ks)
      af[ks] = *(const bf16x8*)&beta_s[(wv * 16 + l15) * 136 + ks * 32 + qd * 8];
#pragma unroll
    for (int nt = 0; nt < 3; ++nt) acc[nt] = (f32x4){0.f, 0.f, 0.f, 0.f};
#pragma unroll
    for (int ks = 0; ks < 4; ++ks) {
#pragma unroll
      for (int nt = 0; nt < 3; ++nt) {
        const bf16x8 bf = *(const bf16x8*)&sdT_s[(nt * 16 + l15) * 136 + ks * 32 + qd * 8];
        acc[nt] = __builtin_amdgcn_mfma_f32_16x16x32_bf16(af[ks], bf, acc[nt], 0, 0, 0);
      }
    }
#pragma unroll
    for (int nt = 0; nt < 3; ++nt) vtv[nt] = vt_s[nt * 16 + l15];
  }
  __syncthreads();   // all beta_s/sdT_s reads complete before aliased writes

  // v_posed -> pos_s[b][v*4+c]; C/D layout: col=lane&15, row=quad*4+reg
  if (wv < 4) {
#pragma unroll
    for (int nt = 0; nt < 3; ++nt) {
      const int n = nt * 16 + l15;
      const int v = n / 3, c = n - 3 * v;
#pragma unroll
      for (int r = 0; r < 4; ++r) {
        const int m = wv * 16 + qd * 4 + r;   // batch
        pos_s[m * 68 + v * 4 + c] = acc[nt][r] + vtv[nt];
      }
    }
  }
  __syncthreads();

  // min/max over the 16 verts: thread t<192 handles (b=t/3, c=t%3)
  if (t < 192) {
    const int b = t / 3, c = t % 3;
    float lo = 1e30f, hi = -1e30f;
#pragma unroll
    for (int v = 0; v < TVJ; ++v) {
      const float val = pos_s[b * 68 + v * 4 + c];
      lo = fminf(lo, val); hi = fmaxf(hi, val);
    }
    pmn[((j * NSUB + s) * B + b) * 3 + c] = lo;
    pmx[((j * NSUB + s) * B + b) * 3 + c] = hi;
  }
}

// ---------------------------------------------------------------------------
// Kernel 2: J finalize + rodrigues + kinematic chain + translation corr.
// (unchanged)
// ---------------------------------------------------------------------------
__global__ void k_chain(const float* __restrict__ pose,
                        const int*   __restrict__ parent,
                        const float* __restrict__ pmn,
                        const float* __restrict__ pmx,
                        const float* __restrict__ beta,
                        const float* __restrict__ trans,
                        unsigned short* __restrict__ G1A,
                        unsigned short* __restrict__ beta_bf) {
  const int b = blockIdx.x;
  const int t = threadIdx.x;  // 64

  __shared__ float R[NJ][9];
  __shared__ float Jl[NJ][3];
  __shared__ float G[NJ][12];
  __shared__ float G1c[NJ][12];

  if (t < NJ) {
    const float x = pose[b * NJ * 3 + t * 3 + 0];
    const float y = pose[b * NJ * 3 + t * 3 + 1];
    const float z = pose[b * NJ * 3 + t * 3 + 2];
    const float th = fmaxf(sqrtf(x * x + y * y + z * z), 1e-6f);
    const float xh = x / th, yh = y / th, zh = z / th;
    const float c = cosf(th), s = sinf(th), o = 1.0f - c;
    R[t][0] = c + o * xh * xh;      R[t][1] = o * xh * yh - s * zh; R[t][2] = o * xh * zh + s * yh;
    R[t][3] = o * xh * yh + s * zh; R[t][4] = c + o * yh * yh;      R[t][5] = o * yh * zh - s * xh;
    R[t][6] = o * xh * zh - s * yh; R[t][7] = o * yh * zh + s * xh; R[t][8] = c + o * zh * zh;
    if (t == 0) {
      Jl[0][0] = 0.0f; Jl[0][1] = 0.0f; Jl[0][2] = 0.0f;
    } else {
      const int jj = t - 1;
#pragma unroll
      for (int c2 = 0; c2 < 3; ++c2) {
        float lo = 1e30f, hi = -1e30f;
#pragma unroll
        for (int s2 = 0; s2 < NSUB; ++s2) {
          lo = fminf(lo, pmn[((jj * NSUB + s2) * B + b) * 3 + c2]);
          hi = fmaxf(hi, pmx[((jj * NSUB + s2) * B + b) * 3 + c2]);
        }
        Jl[t][c2] = 0.5f * (lo + hi);
      }
    }
  }
  __syncthreads();

  if (t < 12) {
    const int r = t >> 2, c = t & 3;
    G[0][t] = (c < 3) ? R[0][r * 3 + c] : Jl[0][r];
  }
  __syncthreads();

  for (int i = 1; i < NJ; ++i) {
    const int p = parent[i];
    if (t < 12) {
      const int r = t >> 2, c = t & 3;
      const float g0 = G[p][r * 4 + 0];
      const float g1 = G[p][r * 4 + 1];
      const float g2 = G[p][r * 4 + 2];
      float l0, l1, l2, add;
      if (c < 3) {
        l0 = R[i][0 * 3 + c]; l1 = R[i][1 * 3 + c]; l2 = R[i][2 * 3 + c];
        add = 0.0f;
      } else {
        l0 = Jl[i][0] - Jl[p][0]; l1 = Jl[i][1] - Jl[p][1]; l2 = Jl[i][2] - Jl[p][2];
        add = G[p][r * 4 + 3];
      }
      G[i][t] = g0 * l0 + g1 * l1 + g2 * l2 + add;
    }
    __syncthreads();
  }

  for (int e = t; e < NJ * 12; e += 64) {
    const int i = e / 12, rc = e % 12, r = rc >> 2, c = rc & 3;
    float val;
    if (c < 3) {
      val = G[i][rc];
    } else {
      val = G[i][r * 4 + 3] - (G[i][r * 4 + 0] * Jl[i][0] +
                               G[i][r * 4 + 1] * Jl[i][1] +
                               G[i][r * 4 + 2] * Jl[i][2]);
    }
    G1c[i][rc] = val;
  }
  __syncthreads();

  for (int e = t; e < 136; e += 64)
    beta_bf[b * 136 + e] = (e < P) ? rne_bf16(beta[b * P + e]) : (unsigned short)0;

  for (int e = t; e < 512; e += 64) {
    const int m = e >> 5, k = e & 31;
    float val = 0.0f;
    if (m < 12) {
      if (k < NJ) val = G1c[k][m];
      else if (k == NJ && (m & 3) == 3) val = trans[b * 3 + (m >> 2)];
    }
    G1A[(size_t)b * 512 + e] = rne_bf16(val);
  }
}

// ---------------------------------------------------------------------------
// Kernel 3: fused shape-blend GEMM + skinning. TVS=32 (1250 blocks):
// halves the redundant beta_s staging and per-output barrier cost.
// LDS hand-carved from one buffer; vhf (v_posed, f32 [64][128]) aliases
// the dead beta_s+sdT_s staging region after phase 1. Phase 2 stores
// straight to global (384B contiguous per batch-row per block) — pos_s
// round-trip, one barrier, and the copy-out loop are gone.
// ---------------------------------------------------------------------------
__global__ __launch_bounds__(256)
void k_skin(const float* __restrict__ sd,
            const float* __restrict__ vt,
            const float* __restrict__ w,
            const unsigned short* __restrict__ beta_bf,
            const unsigned short* __restrict__ G1A,
            float*       __restrict__ out) {
  const int n0v  = blockIdx.x * TVS;
  const int col0 = n0v * 3;            // 96 columns per block
  const int t  = threadIdx.x;
  const int lane = t & 63, wv = t >> 6;
  const int l15 = lane & 15, q = lane >> 4;

  __shared__ __align__(16) unsigned char smem[46464];
  unsigned short* beta_s = (unsigned short*)smem;             // [64][136]  17408 B
  unsigned short* sdT_s  = (unsigned short*)(smem + 17408);   // [96][136]  26112 B
  unsigned short* wT_s   = (unsigned short*)(smem + 43520);   // [32][40]    2560 B
  float*          vt_s   = (float*)(smem + 46080);            // [96]         384 B
  float*          vhf    = (float*)smem;                      // alias [64][128] f32

  for (int e = t; e < 1088; e += 256)
    ((uint4*)beta_s)[e] = ((const uint4*)beta_bf)[e];
  for (int task = t; task < 1536; task += 256) {
    const int n = task % 96, kg = task / 96;
    unsigned pk[4];
#pragma unroll
    for (int h = 0; h < 4; ++h) {
      const int k0 = kg * 8 + 2 * h;
      float f0 = 0.0f, f1 = 0.0f;
      if (k0 < P)     f0 = sd[(size_t)k0 * (3 * NV) + col0 + n];
      if (k0 + 1 < P) f1 = sd[(size_t)(k0 + 1) * (3 * NV) + col0 + n];
      pk[h] = (unsigned)rne_bf16(f0) | ((unsigned)rne_bf16(f1) << 16);
    }
    *(uint4*)&sdT_s[n * 136 + kg * 8] = make_uint4(pk[0], pk[1], pk[2], pk[3]);
  }
  for (int e = t; e < 1024; e += 256) {
    const int n = e >> 5, k = e & 31;
    float val = (k < NJ) ? w[(n0v + n) * NJ + k] : (k == NJ ? 1.0f : 0.0f);
    wT_s[n * 40 + k] = rne_bf16(val);
  }
  if (t < 96) vt_s[t] = vt[col0 + t];
  __syncthreads();

  // phase 1: D(64x96) = beta(64x128) @ sdT(128x96); wave = M-tile of 16 batches
  bf16x8 af[4];
#pragma unroll
  for (int ks = 0; ks < 4; ++ks)
    af[ks] = *(const bf16x8*)&beta_s[(wv * 16 + l15) * 136 + ks * 32 + q * 8];
  f32x4 acc[6];
#pragma unroll
  for (int nt = 0; nt < 6; ++nt) acc[nt] = (f32x4){0.f, 0.f, 0.f, 0.f};
#pragma unroll
  for (int ks = 0; ks < 4; ++ks) {
#pragma unroll
    for (int nt = 0; nt < 6; ++nt) {
      const bf16x8 bf = *(const bf16x8*)&sdT_s[(nt * 16 + l15) * 136 + ks * 32 + q * 8];
      acc[nt] = __builtin_amdgcn_mfma_f32_16x16x32_bf16(af[ks], bf, acc[nt], 0, 0, 0);
    }
  }
  __syncthreads();   // all beta_s/sdT_s fragment reads done before aliased writes

  // v_posed -> vhf[b][v*4+c]  (vt_s lives outside the alias region)
#pragma unroll
  for (int nt = 0; nt < 6; ++nt) {
    const int n = nt * 16 + l15;
    const int v = n / 3, c = n - 3 * v;
    const float vtn = vt_s[n];
#pragma unroll
    for (int r = 0; r < 4; ++r) {
      const int m = wv * 16 + q * 4 + r;   // batch
      vhf[m * 128 + v * 4 + c] = acc[nt][r] + vtn;
    }
  }
  __syncthreads();

  // phase 2: per batch b, T = G1A(b) @ w^T via MFMA; dot with vh; store direct.
  const bf16x8 wf0 = *(const bf16x8*)&wT_s[l15 * 40 + q * 8];
  const bf16x8 wf1 = *(const bf16x8*)&wT_s[(16 + l15) * 40 + q * 8];
  const f32x4 zero = (f32x4){0.f, 0.f, 0.f, 0.f};
#pragma unroll 4
  for (int bi = 0; bi < 16; ++bi) {
    const int b = wv * 16 + bi;
    const bf16x8 gf = *(const bf16x8*)&G1A[(size_t)b * 512 + l15 * 32 + q * 8];
    const f32x4 d0 = __builtin_amdgcn_mfma_f32_16x16x32_bf16(gf, wf0, zero, 0, 0, 0);
    const f32x4 d1 = __builtin_amdgcn_mfma_f32_16x16x32_bf16(gf, wf1, zero, 0, 0, 0);
    const float4 vh0 = *(const float4*)&vhf[b * 128 + l15 * 4];
    const float4 vh1 = *(const float4*)&vhf[b * 128 + 64 + l15 * 4];
    if (q < 3) {
      out[(size_t)b * (NV * 3) + col0 + l15 * 3 + q] =
          d0[0] * vh0.x + d0[1] * vh0.y + d0[2] * vh0.z + d0[3];
      out[(size_t)b * (NV * 3) + col0 + 48 + l15 * 3 + q] =
          d1[0] * vh1.x + d1[1] * vh1.y + d1[2] * vh1.z + d1[3];
    }
  }
}

// ---------------------------------------------------------------------------
// Kernel 4: skeleton keypoints from posed (unchanged).
// ---------------------------------------------------------------------------
__global__ void k_skel(const float* __restrict__ posed,
                       const int*   __restrict__ joint_idx,
                       const int*   __restrict__ add_idx,
                       float*       __restrict__ skel) {
  const int j = blockIdx.x;   // 0..29
  const int b = blockIdx.y;   // 0..63
  const int t = threadIdx.x;  // 0..127
  const int idx = (j < 23) ? joint_idx[j * KG + t] : add_idx[(j - 23) * KG + t];

  const float* p = posed + (size_t)b * NV * 3 + (size_t)idx * 3;
  float mn[3], mx[3];
#pragma unroll
  for (int c = 0; c < 3; ++c) { mn[c] = p[c]; mx[c] = p[c]; }
#pragma unroll
  for (int off = 32; off > 0; off >>= 1) {
#pragma unroll
    for (int c = 0; c < 3; ++c) {
      mn[c] = fminf(mn[c], __shfl_down(mn[c], off));
      mx[c] = fmaxf(mx[c], __shfl_down(mx[c], off));
    }
  }
  __shared__ float s_mn[2][3], s_mx[2][3];
  const int wave = t >> 6, lane = t & 63;
  if (lane == 0) {
#pragma unroll
    for (int c = 0; c < 3; ++c) { s_mn[wave][c] = mn[c]; s_mx[wave][c] = mx[c]; }
  }
  __syncthreads();
  if (t == 0) {
#pragma unroll
    for (int c = 0; c < 3; ++c) {
      float lo = fminf(s_mn[0][c], s_mn[1][c]);
      float hi = fmaxf(s_mx[0][c], s_mx[1][c]);
      skel[(b * NSK + 1 + j) * 3 + c] = 0.5f * (lo + hi);
      if (j == 0) skel[(b * NSK + 0) * 3 + c] = 0.0f;
    }
  }
}

// ---------------------------------------------------------------------------
extern "C" void kernel_launch(void* const* d_in, const int* in_sizes, int n_in,
                              void* d_out, int out_size, void* d_ws, size_t ws_size,
                              hipStream_t stream) {
  const float* beta     = (const float*)d_in[0];
  const float* pose     = (const float*)d_in[1];
  const float* trans    = (const float*)d_in[2];
  const float* sd       = (const float*)d_in[3];
  const float* vt       = (const float*)d_in[4];
  const float* w        = (const float*)d_in[5];
  // d_in[6] = reorder_index (identity arange -> unused)
  const int* parent     = (const int*)d_in[7];
  const int* joint_idx  = (const int*)d_in[8];
  const int* add_idx    = (const int*)d_in[9];

  float* out = (float*)d_out;
  unsigned short* G1A     = (unsigned short*)d_ws;            // 64*512 us
  unsigned short* beta_bf = G1A + B * 512;                    // 64*136 us
  float* pmn = (float*)(beta_bf + B * 136);                   // 23*8*64*3 f
  float* pmx = pmn + 23 * NSUB * B * 3;

  k_jpart<<<dim3(23, NSUB), 512, 0, stream>>>(beta, sd, vt, joint_idx, pmn, pmx);
  k_chain<<<B, 64, 0, stream>>>(pose, parent, pmn, pmx, beta, trans, G1A, beta_bf);
  k_skin <<<NV / TVS, 256, 0, stream>>>(sd, vt, w, beta_bf, G1A, out);
  k_skel <<<dim3(30, B), 128, 0, stream>>>(out, joint_idx, add_idx,
                                           out + (size_t)B * NV * 3);
}